// Round 23
// baseline (530.142 us; speedup 1.0000x reference)
//
#include <hip/hip_runtime.h>
#include <hip/hip_cooperative_groups.h>

namespace cg = cooperative_groups;

#define GNX 64
#define GNY 64
#define GNSH 32
#define NTH 1024
#define MATN 4096   // 64*64 float2 per matrix in workspace

// ws layout, units of matrices (float2[MATN]). Slot e written exactly once
// across all levels. Level 0 stores RAW W into SLO[e] (readers scale).
// After the matrices: 64 int dataflow flags.
#define WS_SLO 0
#define WS_SHI 64
#define WS_CNW 128
#define WS_MATS 192

__device__ __forceinline__ float2 cmulf(float2 a, float2 b) {
    return make_float2(a.x * b.x - a.y * b.y, a.x * b.y + a.y * b.x);
}
__device__ __forceinline__ float2 crecipf(float2 a) {
    float d = a.x * a.x + a.y * a.y;
    float inv = __builtin_amdgcn_rcpf(d);
    return make_float2(a.x * inv, -a.y * inv);
}
__device__ __forceinline__ float scal_f(const void* p) {
    int v = *(const int*)p;
    return (v >= -1000000 && v <= 1000000) ? (float)v : __int_as_float(v);
}
__device__ __forceinline__ int scal_i(const void* p) {
    int v = *(const int*)p;
    return (v >= -1000000 && v <= 1000000) ? v : (int)__int_as_float(v);
}

// ---------------- r13/r16/r17-validated blocked Gauss-Jordan ----------------
#define PUPD(QE, RR) { \
    float2 pc_; \
    pc_.x = __shfl(QE.x, myl | k); pc_.y = __shfl(QE.y, myl | k); \
    if ((RR) == k) { \
        QE = ck ? pr : cmulf(pr, prow); \
    } else { \
        float2 t_ = cmulf(pc_, pr); \
        if (ck) { QE = make_float2(-t_.x, -t_.y); } \
        else { \
            QE.x -= t_.x * prow.x - t_.y * prow.y; \
            QE.y -= t_.x * prow.y + t_.y * prow.x; \
        } \
    } }

#define PINV16(KK) { \
    if (q == 0) { \
        const int hi = c >> 4, cc = c & 15; \
        const int myl = hi << 4; \
        float2 q0 = rowpanel[hi][(KK) + cc]; \
        float2 q1 = rowpanel[4 + hi][(KK) + cc]; \
        float2 q2 = rowpanel[8 + hi][(KK) + cc]; \
        float2 q3 = rowpanel[12 + hi][(KK) + cc]; \
        for (int k = 0; k < 16; ++k) { \
            int ksel = k >> 2; \
            float2 sv = ksel == 0 ? q0 : ksel == 1 ? q1 : ksel == 2 ? q2 : q3; \
            int rl = (k & 3) << 4; \
            float2 prow, pkk; \
            prow.x = __shfl(sv.x, rl | cc); prow.y = __shfl(sv.y, rl | cc); \
            pkk.x  = __shfl(sv.x, rl | k);  pkk.y  = __shfl(sv.y, rl | k); \
            float2 pr = crecipf(pkk); \
            bool ck = (cc == k); \
            PUPD(q0, hi) \
            PUPD(q1, 4 + hi) \
            PUPD(q2, 8 + hi) \
            PUPD(q3, 12 + hi) \
        } \
        PinvS[hi][cc] = q0;      PinvS[4 + hi][cc] = q1; \
        PinvS[8 + hi][cc] = q2;  PinvS[12 + hi][cc] = q3; \
    } }

#define BLOCKSTEP(KK, AB, RB, AX, RX, AY, RY, AZ, RZ) { \
    rowpanel[q][c] = AB; \
    if (c >= (KK) && c < (KK) + 16) { \
        int j_ = c - (KK); \
        colpan[RB][j_] = AB; colpan[RX][j_] = AX; \
        colpan[RY][j_] = AY; colpan[RZ][j_] = AZ; \
    } \
    __syncthreads(); \
    PINV16(KK) \
    __syncthreads(); \
    { \
        bool inb = (c >= (KK)) && (c < (KK) + 16); \
        float2 acc = make_float2(0.0f, 0.0f); \
        _Pragma("unroll") \
        for (int j_ = 0; j_ < 16; ++j_) { \
            float2 pj = PinvS[q][j_]; \
            float2 rj = rowpanel[j_][c]; \
            acc.x += pj.x * rj.x - pj.y * rj.y; \
            acc.y += pj.x * rj.y + pj.y * rj.x; \
        } \
        float2 nb = inb ? PinvS[q][c - (KK)] : acc; \
        newrow[q][c] = nb; \
        AB = nb; \
    } \
    __syncthreads(); \
    { \
        bool inb = (c >= (KK)) && (c < (KK) + 16); \
        float2 sx = {0,0}, sy_ = {0,0}, sz = {0,0}; \
        _Pragma("unroll") \
        for (int j_ = 0; j_ < 16; ++j_) { \
            float2 nr = newrow[j_][c]; \
            float2 cx = colpan[RX][j_]; \
            float2 cy = colpan[RY][j_]; \
            float2 cz = colpan[RZ][j_]; \
            sx.x += cx.x * nr.x - cx.y * nr.y; sx.y += cx.x * nr.y + cx.y * nr.x; \
            sy_.x += cy.x * nr.x - cy.y * nr.y; sy_.y += cy.x * nr.y + cy.y * nr.x; \
            sz.x += cz.x * nr.x - cz.y * nr.y; sz.y += cz.x * nr.y + cz.y * nr.x; \
        } \
        AX.x = (inb ? 0.0f : AX.x) - sx.x;  AX.y = (inb ? 0.0f : AX.y) - sx.y; \
        AY.x = (inb ? 0.0f : AY.x) - sy_.x; AY.y = (inb ? 0.0f : AY.y) - sy_.y; \
        AZ.x = (inb ? 0.0f : AZ.x) - sz.x;  AZ.y = (inb ? 0.0f : AZ.y) - sz.y; \
    } \
    __syncthreads(); }

#define INVERT() { \
    BLOCKSTEP(0,  a0, r0, a1, r1, a2, r2, a3, r3) \
    BLOCKSTEP(16, a1, r1, a0, r0, a2, r2, a3, r3) \
    BLOCKSTEP(32, a2, r2, a0, r0, a3, r3, a1, r1) \
    BLOCKSTEP(48, a3, r3, a0, r0, a1, r1, a2, r2) }

#define CMAC(AC, Aa, Bb) { \
    AC.x += Aa.x * Bb.x - Aa.y * Bb.y; \
    AC.y += Aa.x * Bb.y + Aa.y * Bb.x; }

#define MM(Y0, Y1, Y2, Y3, AEXPR, BEXPR) { \
    Y0 = make_float2(0,0); Y1 = Y0; Y2 = Y0; Y3 = Y0; \
    _Pragma("unroll 4") \
    for (int k_ = 0; k_ < GNX; ++k_) { \
        float2 b_ = BEXPR(k_); \
        { float2 a_ = AEXPR(r0, k_); CMAC(Y0, a_, b_) } \
        { float2 a_ = AEXPR(r1, k_); CMAC(Y1, a_, b_) } \
        { float2 a_ = AEXPR(r2, k_); CMAC(Y2, a_, b_) } \
        { float2 a_ = AEXPR(r3, k_); CMAC(Y3, a_, b_) } \
    } }

#define AG_CP(r, k)  Cpg[(r) * GNX + (k)]
#define AG_CET(r, k) Ceg[(k) * GNX + (r)]
#define AL_MSH(r, k) Msh[r][k]
#define AL_MXT(r, k) MXT[k][r]
#define BL_MSH(k)    Msh[k][c]
#define BL_MXT(k)    MXT[k][c]
#define BG_CE(k)     Ceg[(k) * GNX + c]

// 64KB LDS overlay views from a passed base pointer:
// Msh | { INVERT scratch (dead outside INVERT) / MXT }
#define SHARED_VIEWS_FROM(LB) \
    float2 (*Msh)[GNX]      = (float2(*)[GNX])(LB); \
    float2 (*MXT)[GNX]      = (float2(*)[GNX])((LB) + 4096); \
    float2 (*rowpanel)[GNX] = (float2(*)[GNX])((LB) + 4096); \
    float2 (*newrow)[GNX]   = (float2(*)[GNX])((LB) + 5120); \
    float2 (*colpan)[16]    = (float2(*)[16])((LB) + 6144); \
    float2 (*PinvS)[16]     = (float2(*)[16])((LB) + 7168);

#define BDROW(AE, RE, J) { \
    float2 v_ = make_float2(0.0f, 0.0f); \
    if ((RE) == c) { \
        float vv = vel[(J) * GNX + c]; \
        float iv2 = 1.0f / (vv * vv); \
        v_.x = w2re * iv2 - 4.0f * inv_h2; \
        v_.y = w2im * iv2; \
    } else if (((RE) - c) * ((RE) - c) == 1) { \
        v_.x = inv_h2; \
    } \
    AE = v_; }

#define SUBC(Pp, SC) { \
    float2 t0_ = Pp[r0 * GNX + c], t1_ = Pp[r1 * GNX + c]; \
    float2 t2_ = Pp[r2 * GNX + c], t3_ = Pp[r3 * GNX + c]; \
    a0.x -= (SC) * t0_.x; a0.y -= (SC) * t0_.y; \
    a1.x -= (SC) * t1_.x; a1.y -= (SC) * t1_.y; \
    a2.x -= (SC) * t2_.x; a2.y -= (SC) * t2_.y; \
    a3.x -= (SC) * t3_.x; a3.y -= (SC) * t3_.y; }

// D~_e = D_e - sum_{l'<LVL} contributions. l'==0 slots hold RAW W (scale c2).
#define FOLD_CONTRIB(E, LVL) { \
    for (int lp = 0; lp < (LVL); ++lp) { \
        int s2 = 1 << lp; \
        float sc_ = (lp == 0) ? c2 : 1.0f; \
        if ((E) - s2 >= 0) { \
            const float2* P_ = ws + (size_t)(((lp == 0) ? WS_SLO : WS_SHI) + (E) - s2) * MATN; \
            SUBC(P_, sc_) \
        } \
        if ((E) + s2 <= GNX - 1) { \
            const float2* P_ = ws + (size_t)(WS_SLO + (E) + s2) * MATN; \
            SUBC(P_, sc_) \
        } \
    } }

#define SCST(Y) { Y.x *= cs; Y.y *= cs; }

// Common prologue: build D~_e, invert -> W in a0..a3 (rows r0..r3, col c).
#define ELIM_W_PROLOGUE() \
    BDROW(a0, r0, e) BDROW(a1, r1, e) BDROW(a2, r2, e) BDROW(a3, r3, e) \
    FOLD_CONTRIB(e, lvl) \
    INVERT()

// ---------------- dataflow flags (coop path) --------------------------------
// Producer: all writes drained -> fence -> one atomicAdd. Consumer: thread 0
// spins (device-scope RMW read) then block-wide acquire fence.
__device__ __forceinline__ void fence_and_mark(int* flag) {
    __threadfence();
    __syncthreads();
    if (threadIdx.x == 0) atomicAdd(flag, 1);
}
__device__ __forceinline__ void wait_deps(int* flags, int e, int lvl) {
    if (threadIdx.x == 0) {
        for (int lp = 0; lp < lvl; ++lp) {
            int s2 = 1 << lp;
            int tgt = (lp == 0) ? 1 : 3;   // L0: 1 block; L1+: 3 role-blocks
            if (e - s2 >= 0)
                while (atomicAdd(&flags[e - s2], 0) < tgt) __builtin_amdgcn_s_sleep(2);
            if (e + s2 <= GNX - 1)
                while (atomicAdd(&flags[e + s2], 0) < tgt) __builtin_amdgcn_s_sleep(2);
        }
    }
    __syncthreads();
    __threadfence();
}

// ---------------- elim body: full 5-MM suite (fallback path + L0) -----------
__device__ __forceinline__ void elim_dev(float2* ldsb, float2* __restrict__ ws,
                                         const float* __restrict__ vel,
                                         float omega, int e, int lvl) {
    SHARED_VIEWS_FROM(ldsb)
    const int tid = threadIdx.x;
    const int c = tid & 63;
    const int q = tid >> 6;
    const int r0 = q, r1 = 16 + q, r2 = 32 + q, r3 = 48 + q;
    const int s = 1 << lvl;
    const bool has_p = (e - s) >= 0;
    const bool has_n = (e + s) <= GNX - 1;
    const float inv_h2 = 1.0f / (25.0f * 25.0f);
    const float c2 = inv_h2 * inv_h2;
    const float w2re = omega * omega * (1.0f - 0.0025f);
    const float w2im = -0.1f * omega * omega;

    float2 a0, a1, a2, a3, y0, y1, y2, y3, z0, z1, z2, z3;
    ELIM_W_PROLOGUE()

    float2* Sl = ws + (size_t)(WS_SLO + e) * MATN;
    float2* Sh = ws + (size_t)(WS_SHI + e) * MATN;
    float2* Cn = ws + (size_t)(WS_CNW + e) * MATN;

    if (lvl == 0) {
        Sl[r0 * GNX + c] = a0; Sl[r1 * GNX + c] = a1;
        Sl[r2 * GNX + c] = a2; Sl[r3 * GNX + c] = a3;
        return;
    }

    Msh[r0][c] = a0; Msh[r1][c] = a1; Msh[r2][c] = a2; Msh[r3][c] = a3;
    __syncthreads();

    const int h = s >> 1;
    const int cbase = (lvl == 1) ? WS_SLO : WS_CNW;
    const float cs = (lvl == 1) ? -c2 : 1.0f;
    const float2* Cpg = ws + (size_t)(cbase + (has_p ? e - h : 0)) * MATN;
    const float2* Ceg = ws + (size_t)(cbase + (has_n ? e + h : 0)) * MATN;

    if (has_p) {
        MM(y0, y1, y2, y3, AG_CP, BL_MSH)
        SCST(y0) SCST(y1) SCST(y2) SCST(y3)
        MXT[c][r0] = y0; MXT[c][r1] = y1;
        MXT[c][r2] = y2; MXT[c][r3] = y3;
        __syncthreads();
        MM(z0, z1, z2, z3, AG_CP, BL_MXT)
        SCST(z0) SCST(z1) SCST(z2) SCST(z3)
        Sl[r0 * GNX + c] = z0; Sl[r1 * GNX + c] = z1;
        Sl[r2 * GNX + c] = z2; Sl[r3 * GNX + c] = z3;
        if (has_n) {
            MM(z0, z1, z2, z3, AL_MXT, BG_CE)
            SCST(z0) SCST(z1) SCST(z2) SCST(z3)
            Cn[r0 * GNX + c] = make_float2(-z0.x, -z0.y);
            Cn[r1 * GNX + c] = make_float2(-z1.x, -z1.y);
            Cn[r2 * GNX + c] = make_float2(-z2.x, -z2.y);
            Cn[r3 * GNX + c] = make_float2(-z3.x, -z3.y);
        }
    }
    if (has_n) {
        MM(y0, y1, y2, y3, AL_MSH, BG_CE)
        SCST(y0) SCST(y1) SCST(y2) SCST(y3)
        __syncthreads();
        Msh[r0][c] = y0; Msh[r1][c] = y1;
        Msh[r2][c] = y2; Msh[r3][c] = y3;
        __syncthreads();
        MM(z0, z1, z2, z3, AG_CET, BL_MSH)
        SCST(z0) SCST(z1) SCST(z2) SCST(z3)
        Sh[r0 * GNX + c] = z0; Sh[r1 * GNX + c] = z1;
        Sh[r2 * GNX + c] = z2; Sh[r3 * GNX + c] = z3;
    }
}

// ------------- elim body: role-split (coop path; 2 MMs per block) -----------
__device__ __forceinline__ void elim_role(float2* ldsb, float2* __restrict__ ws,
                                          const float* __restrict__ vel,
                                          float omega, int e, int lvl, int role) {
    const int s = 1 << lvl;
    const bool has_p = (e - s) >= 0;
    const bool has_n = (e + s) <= GNX - 1;
    if (role == 0 && !has_p) return;
    if (role == 1 && !has_n) return;
    if (role == 2 && !(has_p && has_n)) return;

    SHARED_VIEWS_FROM(ldsb)
    const int tid = threadIdx.x;
    const int c = tid & 63;
    const int q = tid >> 6;
    const int r0 = q, r1 = 16 + q, r2 = 32 + q, r3 = 48 + q;
    const float inv_h2 = 1.0f / (25.0f * 25.0f);
    const float c2 = inv_h2 * inv_h2;
    const float w2re = omega * omega * (1.0f - 0.0025f);
    const float w2im = -0.1f * omega * omega;

    float2 a0, a1, a2, a3, y0, y1, y2, y3, z0, z1, z2, z3;
    ELIM_W_PROLOGUE()

    Msh[r0][c] = a0; Msh[r1][c] = a1; Msh[r2][c] = a2; Msh[r3][c] = a3;
    __syncthreads();

    const int h = s >> 1;
    const int cbase = (lvl == 1) ? WS_SLO : WS_CNW;
    const float cs = (lvl == 1) ? -c2 : 1.0f;
    const float2* Cpg = ws + (size_t)(cbase + (has_p ? e - h : 0)) * MATN;
    const float2* Ceg = ws + (size_t)(cbase + (has_n ? e + h : 0)) * MATN;

    if (role == 0) {
        float2* Sl = ws + (size_t)(WS_SLO + e) * MATN;
        MM(y0, y1, y2, y3, AG_CP, BL_MSH)
        SCST(y0) SCST(y1) SCST(y2) SCST(y3)
        MXT[c][r0] = y0; MXT[c][r1] = y1;
        MXT[c][r2] = y2; MXT[c][r3] = y3;
        __syncthreads();
        MM(z0, z1, z2, z3, AG_CP, BL_MXT)
        SCST(z0) SCST(z1) SCST(z2) SCST(z3)
        Sl[r0 * GNX + c] = z0; Sl[r1 * GNX + c] = z1;
        Sl[r2 * GNX + c] = z2; Sl[r3 * GNX + c] = z3;
    } else if (role == 1) {
        float2* Sh = ws + (size_t)(WS_SHI + e) * MATN;
        MM(y0, y1, y2, y3, AL_MSH, BG_CE)
        SCST(y0) SCST(y1) SCST(y2) SCST(y3)
        __syncthreads();
        Msh[r0][c] = y0; Msh[r1][c] = y1;
        Msh[r2][c] = y2; Msh[r3][c] = y3;
        __syncthreads();
        MM(z0, z1, z2, z3, AG_CET, BL_MSH)
        SCST(z0) SCST(z1) SCST(z2) SCST(z3)
        Sh[r0 * GNX + c] = z0; Sh[r1 * GNX + c] = z1;
        Sh[r2 * GNX + c] = z2; Sh[r3 * GNX + c] = z3;
    } else {
        float2* Cn = ws + (size_t)(WS_CNW + e) * MATN;
        MM(y0, y1, y2, y3, AG_CP, BL_MSH)
        SCST(y0) SCST(y1) SCST(y2) SCST(y3)
        MXT[c][r0] = y0; MXT[c][r1] = y1;
        MXT[c][r2] = y2; MXT[c][r3] = y3;
        __syncthreads();
        MM(z0, z1, z2, z3, AL_MXT, BG_CE)
        SCST(z0) SCST(z1) SCST(z2) SCST(z3)
        Cn[r0 * GNX + c] = make_float2(-z0.x, -z0.y);
        Cn[r1 * GNX + c] = make_float2(-z1.x, -z1.y);
        Cn[r2 * GNX + c] = make_float2(-z2.x, -z2.y);
        Cn[r3 * GNX + c] = make_float2(-z3.x, -z3.y);
    }
}

// Fused L5 (e=34, has_p only) + final: Slo[34] never leaves registers.
__device__ __forceinline__ void tail_dev(float2* ldsb, float2* __restrict__ ws,
                                         const float* __restrict__ vel,
                                         const int* __restrict__ sxs,
                                         float omega, float amp,
                                         float* __restrict__ out, int out_size) {
    SHARED_VIEWS_FROM(ldsb)
    const int tid = threadIdx.x;
    const int c = tid & 63;
    const int q = tid >> 6;
    const int r0 = q, r1 = 16 + q, r2 = 32 + q, r3 = 48 + q;
    const float inv_h2 = 1.0f / (25.0f * 25.0f);
    const float c2 = inv_h2 * inv_h2;
    const float w2re = omega * omega * (1.0f - 0.0025f);
    const float w2im = -0.1f * omega * omega;
    float2 a0, a1, a2, a3, y0, y1, y2, y3, z0, z1, z2, z3;

    // L5: W34 = (D_34 - folds)^-1
    {
        const int e = 34, lvl = 5;
        ELIM_W_PROLOGUE()
    }
    Msh[r0][c] = a0; Msh[r1][c] = a1; Msh[r2][c] = a2; Msh[r3][c] = a3;
    __syncthreads();
    const float2* Cpg = ws + (size_t)(WS_CNW + 18) * MATN;  // C(2<->34) from L4
    MM(y0, y1, y2, y3, AG_CP, BL_MSH)        // X = Cn18 * W34   (cs = 1)
    MXT[c][r0] = y0; MXT[c][r1] = y1; MXT[c][r2] = y2; MXT[c][r3] = y3;
    __syncthreads();
    MM(z0, z1, z2, z3, AG_CP, BL_MXT)        // Slo[34] = Cn18 * X^T -> registers
    __syncthreads();                         // MXT reads done; scratch reusable

    // final: D~_2 = D_2 - folds(lp 0..4) - Slo34(regs)
    BDROW(a0, r0, 2) BDROW(a1, r1, 2) BDROW(a2, r2, 2) BDROW(a3, r3, 2)
    FOLD_CONTRIB(2, 5)
    a0.x -= z0.x; a0.y -= z0.y; a1.x -= z1.x; a1.y -= z1.y;
    a2.x -= z2.x; a2.y -= z2.y; a3.x -= z3.x; a3.y -= z3.y;
    INVERT()
    Msh[r0][c] = a0; Msh[r1][c] = a1; Msh[r2][c] = a2; Msh[r3][c] = a3;
    __syncthreads();
    // Graded: out[s*64 + x] = amp * Re(M[x, sxs[s]]) (r3/r4 forensics)
    for (int idx = tid; idx < GNSH * GNX; idx += NTH) {
        int sh_ = idx >> 6, x = idx & 63;
        int sx = sxs[sh_] & 63;
        if (idx < out_size) out[idx] = amp * Msh[x][sx].x;
    }
    for (int idx = GNSH * GNX + tid; idx < out_size; idx += NTH) out[idx] = 0.0f;
}

// ------------- single cooperative kernel: dataflow-flag levels --------------
#define NBLK 48
__global__ __launch_bounds__(NTH) void bcr_coop(
    float2* __restrict__ ws, const float* __restrict__ vel,
    const int* __restrict__ sxs, const void* om_p, const void* amp_p,
    float* __restrict__ out, int out_size) {
    __shared__ float2 ldsbuf[8192];
    cg::grid_group grid = cg::this_grid();
    int* flags = (int*)(ws + (size_t)WS_MATS * MATN);
    const int bid = (int)blockIdx.x;
    const int eidx = bid / 3, role = bid % 3;
    const float omega = scal_f(om_p);

    // Zero flags (all blocks redundantly; benign identical writes), then the
    // ONLY grid sync — guards against stale flags across graph replays.
    for (int i = threadIdx.x; i < GNX; i += NTH) flags[i] = 0;
    grid.sync();

    if (bid < 32) {                      // L0 (no deps)
        int e = 1 + bid * 2;
        elim_dev(ldsbuf, ws, vel, omega, e, 0);
        fence_and_mark(&flags[e]);
    }
    if (eidx < 16) {                     // L1
        int e = 0 + eidx * 4;
        wait_deps(flags, e, 1);
        elim_role(ldsbuf, ws, vel, omega, e, 1, role);
        fence_and_mark(&flags[e]);
    }
    if (eidx < 8) {                      // L2
        int e = 6 + eidx * 8;
        wait_deps(flags, e, 2);
        elim_role(ldsbuf, ws, vel, omega, e, 2, role);
        fence_and_mark(&flags[e]);
    }
    if (eidx < 4) {                      // L3
        int e = 10 + eidx * 16;
        wait_deps(flags, e, 3);
        elim_role(ldsbuf, ws, vel, omega, e, 3, role);
        fence_and_mark(&flags[e]);
    }
    if (eidx < 2) {                      // L4
        int e = 18 + eidx * 32;
        wait_deps(flags, e, 4);
        elim_role(ldsbuf, ws, vel, omega, e, 4, role);
        fence_and_mark(&flags[e]);
    }
    if (bid == 0) {                      // tail: L5 (e=34) + final (e=2)
        wait_deps(flags, 34, 5);
        wait_deps(flags, 2, 5);
        tail_dev(ldsbuf, ws, vel, sxs, omega, scal_f(amp_p), out, out_size);
    }
}

// ---------------- fallback A: r17 multi-dispatch (proven 612us) -------------
__global__ __launch_bounds__(NTH) void bcr_elim(float2* __restrict__ ws,
                                                const float* __restrict__ vel,
                                                const void* om_p,
                                                int ebase, int estep, int lvl) {
    __shared__ float2 ldsbuf[8192];
    elim_dev(ldsbuf, ws, vel, scal_f(om_p),
             ebase + (int)blockIdx.x * estep, lvl);
}

__global__ __launch_bounds__(NTH) void bcr_final(
    float2* __restrict__ ws, const float* __restrict__ vel,
    const int* __restrict__ sxs, const void* om_p, const void* amp_p,
    float* __restrict__ out, int out_size) {
    __shared__ float2 ldsbuf[8192];
    SHARED_VIEWS_FROM(ldsbuf)
    const int tid = threadIdx.x;
    const int c = tid & 63;
    const int q = tid >> 6;
    const int r0 = q, r1 = 16 + q, r2 = 32 + q, r3 = 48 + q;
    const float omega = scal_f(om_p);
    const float amp = scal_f(amp_p);
    const float inv_h2 = 1.0f / (25.0f * 25.0f);
    const float c2 = inv_h2 * inv_h2;
    const float w2re = omega * omega * (1.0f - 0.0025f);
    const float w2im = -0.1f * omega * omega;
    float2 a0, a1, a2, a3;
    BDROW(a0, r0, 2) BDROW(a1, r1, 2) BDROW(a2, r2, 2) BDROW(a3, r3, 2)
    FOLD_CONTRIB(2, 6)
    INVERT()
    Msh[r0][c] = a0; Msh[r1][c] = a1; Msh[r2][c] = a2; Msh[r3][c] = a3;
    __syncthreads();
    for (int idx = tid; idx < GNSH * GNX; idx += NTH) {
        int sh_ = idx >> 6, x = idx & 63;
        int sx = sxs[sh_] & 63;
        if (idx < out_size) out[idx] = amp * Msh[x][sx].x;
    }
    for (int idx = GNSH * GNX + tid; idx < out_size; idx += NTH) out[idx] = 0.0f;
    (void)MXT;
}

// ---------------- fallback B: r13 single-block RGF --------------------------
__global__ __launch_bounds__(NTH) void rgf_mono(
    const float* __restrict__ vel, const int* __restrict__ sxs,
    const void* sy_p, const void* ry_p, const void* om_p, const void* amp_p,
    float* __restrict__ out, int out_size)
{
    __shared__ float2 ldsbuf[8192];
    SHARED_VIEWS_FROM(ldsbuf)
    const int tid = threadIdx.x;
    const int c = tid & 63;
    const int q = tid >> 6;
    const int r0 = q, r1 = 16 + q, r2 = 32 + q, r3 = 48 + q;

    const float omega = scal_f(om_p);
    const float amp = scal_f(amp_p);
    int jmid_raw = scal_i(sy_p);
    const int jmid = jmid_raw < 0 ? 0 : (jmid_raw > GNY - 1 ? GNY - 1 : jmid_raw);
    (void)ry_p;

    const float inv_h2 = 1.0f / (25.0f * 25.0f);
    const float c2 = inv_h2 * inv_h2;
    const float w2re = omega * omega * (1.0f - 0.0025f);
    const float w2im = -0.1f * omega * omega;

    float2 a0, a1, a2, a3;
    float2 g0 = {0,0}, g1 = {0,0}, g2 = {0,0}, g3 = {0,0};

#define BUILD(AE, GE, RE, J, USEPREV, USEGD) { \
    float2 v; \
    v.x = (USEPREV) ? -c2 * AE.x : 0.0f; \
    v.y = (USEPREV) ? -c2 * AE.y : 0.0f; \
    if (USEGD) { v.x -= c2 * GE.x; v.y -= c2 * GE.y; } \
    if ((RE) == c) { \
        float vv = vel[(J) * GNX + c]; \
        float iv2 = 1.0f / (vv * vv); \
        v.x += w2re * iv2 - 4.0f * inv_h2; \
        v.y += w2im * iv2; \
    } else if (((RE) - c) * ((RE) - c) == 1) { \
        v.x += inv_h2; \
    } \
    AE = v; }

#define BUILD4(J, USEPREV, USEGD) { \
    BUILD(a0, g0, r0, J, USEPREV, USEGD) \
    BUILD(a1, g1, r1, J, USEPREV, USEGD) \
    BUILD(a2, g2, r2, J, USEPREV, USEGD) \
    BUILD(a3, g3, r3, J, USEPREV, USEGD) }

    if (jmid > 0) {
        BUILD4(0, false, false)
        INVERT()
        for (int j = 1; j < jmid; ++j) { BUILD4(j, true, false) INVERT() }
        g0 = a0; g1 = a1; g2 = a2; g3 = a3;
    }
    const bool have_up = (jmid < GNY - 1);
    if (have_up) {
        BUILD4(GNY - 1, false, false)
        INVERT()
        for (int m = GNY - 2; m > jmid; --m) { BUILD4(m, true, false) INVERT() }
    }
    BUILD4(jmid, have_up, jmid > 0)
    INVERT()

    Msh[r0][c] = a0; Msh[r1][c] = a1; Msh[r2][c] = a2; Msh[r3][c] = a3;
    __syncthreads();

    for (int idx = tid; idx < GNSH * GNX; idx += NTH) {
        int s_ = idx >> 6, x = idx & 63;
        int sx = sxs[s_] & 63;
        if (idx < out_size) out[idx] = amp * Msh[x][sx].x;
    }
    for (int idx = GNSH * GNX + tid; idx < out_size; idx += NTH) out[idx] = 0.0f;
    (void)MXT;
}

extern "C" void kernel_launch(void* const* d_in, const int* in_sizes, int n_in,
                              void* d_out, int out_size, void* d_ws, size_t ws_size,
                              hipStream_t stream) {
    (void)in_sizes; (void)n_in;
    const float* vel = (const float*)d_in[0];
    const int* sxs = (const int*)d_in[1];
    const size_t need = (size_t)WS_MATS * MATN * sizeof(float2)
                        + GNX * sizeof(int);  // 6 MB + flags
    if (ws_size >= need) {
        float2* wsp = (float2*)d_ws;
        const float* velp = vel;
        const int* sxsp = sxs;
        const void* omp = d_in[4];
        const void* ampp = d_in[5];
        float* outp = (float*)d_out;
        int osz = out_size;
        void* args[] = {&wsp, (void*)&velp, (void*)&sxsp,
                        (void*)&omp, (void*)&ampp, &outp, &osz};
        hipError_t err = hipLaunchCooperativeKernel(
            (const void*)bcr_coop, dim3(NBLK), dim3(NTH), args, 0, stream);
        if (err == hipSuccess) return;
        (void)hipGetLastError();  // clear; fall back to multi-dispatch (r17)
        static const int EL[6][3] = {
            {32, 1, 2}, {16, 0, 4}, {8, 6, 8},
            {4, 10, 16}, {2, 18, 32}, {1, 34, 64}};
        for (int l = 0; l < 6; ++l) {
            bcr_elim<<<dim3(EL[l][0]), dim3(NTH), 0, stream>>>(
                wsp, vel, d_in[4], EL[l][1], EL[l][2], l);
        }
        bcr_final<<<dim3(1), dim3(NTH), 0, stream>>>(
            wsp, vel, sxs, d_in[4], d_in[5], (float*)d_out, out_size);
    } else {
        rgf_mono<<<dim3(1), dim3(NTH), 0, stream>>>(
            vel, sxs, d_in[2], d_in[3], d_in[4], d_in[5], (float*)d_out, out_size);
    }
}

// Round 24
// 471.236 us; speedup vs baseline: 1.1250x; 1.1250x over previous
//
#include <hip/hip_runtime.h>
#include <hip/hip_cooperative_groups.h>

namespace cg = cooperative_groups;

#define GNX 64
#define GNY 64
#define GNSH 32
#define NTH 1024
#define MATN 4096   // 64*64 float2 per matrix in workspace

// ws layout, units of matrices (float2[MATN]). Slot e written exactly once
// across all levels. Level 0 stores RAW W into SLO[e] (readers scale).
#define WS_SLO 0
#define WS_SHI 64
#define WS_CNW 128
#define WS_MATS 192

__device__ __forceinline__ float2 cmulf(float2 a, float2 b) {
    return make_float2(a.x * b.x - a.y * b.y, a.x * b.y + a.y * b.x);
}
__device__ __forceinline__ float2 crecipf(float2 a) {
    float d = a.x * a.x + a.y * a.y;
    float inv = __builtin_amdgcn_rcpf(d);
    return make_float2(a.x * inv, -a.y * inv);
}
__device__ __forceinline__ float scal_f(const void* p) {
    int v = *(const int*)p;
    return (v >= -1000000 && v <= 1000000) ? (float)v : __int_as_float(v);
}
__device__ __forceinline__ int scal_i(const void* p) {
    int v = *(const int*)p;
    return (v >= -1000000 && v <= 1000000) ? v : (int)__int_as_float(v);
}

// ---------------- r13/r16/r17-validated blocked Gauss-Jordan ----------------
#define PUPD(QE, RR) { \
    float2 pc_; \
    pc_.x = __shfl(QE.x, myl | k); pc_.y = __shfl(QE.y, myl | k); \
    if ((RR) == k) { \
        QE = ck ? pr : cmulf(pr, prow); \
    } else { \
        float2 t_ = cmulf(pc_, pr); \
        if (ck) { QE = make_float2(-t_.x, -t_.y); } \
        else { \
            QE.x -= t_.x * prow.x - t_.y * prow.y; \
            QE.y -= t_.x * prow.y + t_.y * prow.x; \
        } \
    } }

#define PINV16(KK) { \
    if (q == 0) { \
        const int hi = c >> 4, cc = c & 15; \
        const int myl = hi << 4; \
        float2 q0 = rowpanel[hi][(KK) + cc]; \
        float2 q1 = rowpanel[4 + hi][(KK) + cc]; \
        float2 q2 = rowpanel[8 + hi][(KK) + cc]; \
        float2 q3 = rowpanel[12 + hi][(KK) + cc]; \
        for (int k = 0; k < 16; ++k) { \
            int ksel = k >> 2; \
            float2 sv = ksel == 0 ? q0 : ksel == 1 ? q1 : ksel == 2 ? q2 : q3; \
            int rl = (k & 3) << 4; \
            float2 prow, pkk; \
            prow.x = __shfl(sv.x, rl | cc); prow.y = __shfl(sv.y, rl | cc); \
            pkk.x  = __shfl(sv.x, rl | k);  pkk.y  = __shfl(sv.y, rl | k); \
            float2 pr = crecipf(pkk); \
            bool ck = (cc == k); \
            PUPD(q0, hi) \
            PUPD(q1, 4 + hi) \
            PUPD(q2, 8 + hi) \
            PUPD(q3, 12 + hi) \
        } \
        PinvS[hi][cc] = q0;      PinvS[4 + hi][cc] = q1; \
        PinvS[8 + hi][cc] = q2;  PinvS[12 + hi][cc] = q3; \
    } }

#define BLOCKSTEP(KK, AB, RB, AX, RX, AY, RY, AZ, RZ) { \
    rowpanel[q][c] = AB; \
    if (c >= (KK) && c < (KK) + 16) { \
        int j_ = c - (KK); \
        colpan[RB][j_] = AB; colpan[RX][j_] = AX; \
        colpan[RY][j_] = AY; colpan[RZ][j_] = AZ; \
    } \
    __syncthreads(); \
    PINV16(KK) \
    __syncthreads(); \
    { \
        bool inb = (c >= (KK)) && (c < (KK) + 16); \
        float2 acc = make_float2(0.0f, 0.0f); \
        _Pragma("unroll") \
        for (int j_ = 0; j_ < 16; ++j_) { \
            float2 pj = PinvS[q][j_]; \
            float2 rj = rowpanel[j_][c]; \
            acc.x += pj.x * rj.x - pj.y * rj.y; \
            acc.y += pj.x * rj.y + pj.y * rj.x; \
        } \
        float2 nb = inb ? PinvS[q][c - (KK)] : acc; \
        newrow[q][c] = nb; \
        AB = nb; \
    } \
    __syncthreads(); \
    { \
        bool inb = (c >= (KK)) && (c < (KK) + 16); \
        float2 sx = {0,0}, sy_ = {0,0}, sz = {0,0}; \
        _Pragma("unroll") \
        for (int j_ = 0; j_ < 16; ++j_) { \
            float2 nr = newrow[j_][c]; \
            float2 cx = colpan[RX][j_]; \
            float2 cy = colpan[RY][j_]; \
            float2 cz = colpan[RZ][j_]; \
            sx.x += cx.x * nr.x - cx.y * nr.y; sx.y += cx.x * nr.y + cx.y * nr.x; \
            sy_.x += cy.x * nr.x - cy.y * nr.y; sy_.y += cy.x * nr.y + cy.y * nr.x; \
            sz.x += cz.x * nr.x - cz.y * nr.y; sz.y += cz.x * nr.y + cz.y * nr.x; \
        } \
        AX.x = (inb ? 0.0f : AX.x) - sx.x;  AX.y = (inb ? 0.0f : AX.y) - sx.y; \
        AY.x = (inb ? 0.0f : AY.x) - sy_.x; AY.y = (inb ? 0.0f : AY.y) - sy_.y; \
        AZ.x = (inb ? 0.0f : AZ.x) - sz.x;  AZ.y = (inb ? 0.0f : AZ.y) - sz.y; \
    } \
    __syncthreads(); }

#define INVERT() { \
    BLOCKSTEP(0,  a0, r0, a1, r1, a2, r2, a3, r3) \
    BLOCKSTEP(16, a1, r1, a0, r0, a2, r2, a3, r3) \
    BLOCKSTEP(32, a2, r2, a0, r0, a3, r3, a1, r1) \
    BLOCKSTEP(48, a3, r3, a0, r0, a1, r1, a2, r2) }

#define CMAC(AC, Aa, Bb) { \
    AC.x += Aa.x * Bb.x - Aa.y * Bb.y; \
    AC.y += Aa.x * Bb.y + Aa.y * Bb.x; }

#define MM(Y0, Y1, Y2, Y3, AEXPR, BEXPR) { \
    Y0 = make_float2(0,0); Y1 = Y0; Y2 = Y0; Y3 = Y0; \
    _Pragma("unroll 4") \
    for (int k_ = 0; k_ < GNX; ++k_) { \
        float2 b_ = BEXPR(k_); \
        { float2 a_ = AEXPR(r0, k_); CMAC(Y0, a_, b_) } \
        { float2 a_ = AEXPR(r1, k_); CMAC(Y1, a_, b_) } \
        { float2 a_ = AEXPR(r2, k_); CMAC(Y2, a_, b_) } \
        { float2 a_ = AEXPR(r3, k_); CMAC(Y3, a_, b_) } \
    } }

#define AG_CP(r, k)  Cpg[(r) * GNX + (k)]
#define AG_CET(r, k) Ceg[(k) * GNX + (r)]
#define AL_MSH(r, k) Msh[r][k]
#define AL_MXT(r, k) MXT[k][r]
#define BL_MSH(k)    Msh[k][c]
#define BL_MXT(k)    MXT[k][c]
#define BG_CE(k)     Ceg[(k) * GNX + c]

// 64KB LDS overlay views from a passed base pointer:
// Msh | { INVERT scratch (dead outside INVERT) / MXT }
#define SHARED_VIEWS_FROM(LB) \
    float2 (*Msh)[GNX]      = (float2(*)[GNX])(LB); \
    float2 (*MXT)[GNX]      = (float2(*)[GNX])((LB) + 4096); \
    float2 (*rowpanel)[GNX] = (float2(*)[GNX])((LB) + 4096); \
    float2 (*newrow)[GNX]   = (float2(*)[GNX])((LB) + 5120); \
    float2 (*colpan)[16]    = (float2(*)[16])((LB) + 6144); \
    float2 (*PinvS)[16]     = (float2(*)[16])((LB) + 7168);

#define BDROW(AE, RE, J) { \
    float2 v_ = make_float2(0.0f, 0.0f); \
    if ((RE) == c) { \
        float vv = vel[(J) * GNX + c]; \
        float iv2 = 1.0f / (vv * vv); \
        v_.x = w2re * iv2 - 4.0f * inv_h2; \
        v_.y = w2im * iv2; \
    } else if (((RE) - c) * ((RE) - c) == 1) { \
        v_.x = inv_h2; \
    } \
    AE = v_; }

#define SUBC(Pp, SC) { \
    float2 t0_ = Pp[r0 * GNX + c], t1_ = Pp[r1 * GNX + c]; \
    float2 t2_ = Pp[r2 * GNX + c], t3_ = Pp[r3 * GNX + c]; \
    a0.x -= (SC) * t0_.x; a0.y -= (SC) * t0_.y; \
    a1.x -= (SC) * t1_.x; a1.y -= (SC) * t1_.y; \
    a2.x -= (SC) * t2_.x; a2.y -= (SC) * t2_.y; \
    a3.x -= (SC) * t3_.x; a3.y -= (SC) * t3_.y; }

// D~_e = D_e - sum_{l'<LVL} contributions. l'==0 slots hold RAW W (scale c2).
#define FOLD_CONTRIB(E, LVL) { \
    for (int lp = 0; lp < (LVL); ++lp) { \
        int s2 = 1 << lp; \
        float sc_ = (lp == 0) ? c2 : 1.0f; \
        if ((E) - s2 >= 0) { \
            const float2* P_ = ws + (size_t)(((lp == 0) ? WS_SLO : WS_SHI) + (E) - s2) * MATN; \
            SUBC(P_, sc_) \
        } \
        if ((E) + s2 <= GNX - 1) { \
            const float2* P_ = ws + (size_t)(WS_SLO + (E) + s2) * MATN; \
            SUBC(P_, sc_) \
        } \
    } }

#define SCST(Y) { Y.x *= cs; Y.y *= cs; }

// Common prologue: build D~_e, invert -> W in a0..a3 (rows r0..r3, col c).
#define ELIM_W_PROLOGUE() \
    BDROW(a0, r0, e) BDROW(a1, r1, e) BDROW(a2, r2, e) BDROW(a3, r3, e) \
    FOLD_CONTRIB(e, lvl) \
    INVERT()

// ---------------- elim body: full 5-MM suite (fallback path + L0) -----------
__device__ __forceinline__ void elim_dev(float2* ldsb, float2* __restrict__ ws,
                                         const float* __restrict__ vel,
                                         float omega, int e, int lvl) {
    SHARED_VIEWS_FROM(ldsb)
    const int tid = threadIdx.x;
    const int c = tid & 63;
    const int q = tid >> 6;
    const int r0 = q, r1 = 16 + q, r2 = 32 + q, r3 = 48 + q;
    const int s = 1 << lvl;
    const bool has_p = (e - s) >= 0;
    const bool has_n = (e + s) <= GNX - 1;
    const float inv_h2 = 1.0f / (25.0f * 25.0f);
    const float c2 = inv_h2 * inv_h2;
    const float w2re = omega * omega * (1.0f - 0.0025f);
    const float w2im = -0.1f * omega * omega;

    float2 a0, a1, a2, a3, y0, y1, y2, y3, z0, z1, z2, z3;
    ELIM_W_PROLOGUE()

    float2* Sl = ws + (size_t)(WS_SLO + e) * MATN;
    float2* Sh = ws + (size_t)(WS_SHI + e) * MATN;
    float2* Cn = ws + (size_t)(WS_CNW + e) * MATN;

    if (lvl == 0) {
        Sl[r0 * GNX + c] = a0; Sl[r1 * GNX + c] = a1;
        Sl[r2 * GNX + c] = a2; Sl[r3 * GNX + c] = a3;
        return;
    }

    Msh[r0][c] = a0; Msh[r1][c] = a1; Msh[r2][c] = a2; Msh[r3][c] = a3;
    __syncthreads();

    const int h = s >> 1;
    const int cbase = (lvl == 1) ? WS_SLO : WS_CNW;
    const float cs = (lvl == 1) ? -c2 : 1.0f;
    const float2* Cpg = ws + (size_t)(cbase + (has_p ? e - h : 0)) * MATN;
    const float2* Ceg = ws + (size_t)(cbase + (has_n ? e + h : 0)) * MATN;

    if (has_p) {
        MM(y0, y1, y2, y3, AG_CP, BL_MSH)
        SCST(y0) SCST(y1) SCST(y2) SCST(y3)
        MXT[c][r0] = y0; MXT[c][r1] = y1;
        MXT[c][r2] = y2; MXT[c][r3] = y3;
        __syncthreads();
        MM(z0, z1, z2, z3, AG_CP, BL_MXT)
        SCST(z0) SCST(z1) SCST(z2) SCST(z3)
        Sl[r0 * GNX + c] = z0; Sl[r1 * GNX + c] = z1;
        Sl[r2 * GNX + c] = z2; Sl[r3 * GNX + c] = z3;
        if (has_n) {
            MM(z0, z1, z2, z3, AL_MXT, BG_CE)
            SCST(z0) SCST(z1) SCST(z2) SCST(z3)
            Cn[r0 * GNX + c] = make_float2(-z0.x, -z0.y);
            Cn[r1 * GNX + c] = make_float2(-z1.x, -z1.y);
            Cn[r2 * GNX + c] = make_float2(-z2.x, -z2.y);
            Cn[r3 * GNX + c] = make_float2(-z3.x, -z3.y);
        }
    }
    if (has_n) {
        MM(y0, y1, y2, y3, AL_MSH, BG_CE)
        SCST(y0) SCST(y1) SCST(y2) SCST(y3)
        __syncthreads();
        Msh[r0][c] = y0; Msh[r1][c] = y1;
        Msh[r2][c] = y2; Msh[r3][c] = y3;
        __syncthreads();
        MM(z0, z1, z2, z3, AG_CET, BL_MSH)
        SCST(z0) SCST(z1) SCST(z2) SCST(z3)
        Sh[r0 * GNX + c] = z0; Sh[r1 * GNX + c] = z1;
        Sh[r2 * GNX + c] = z2; Sh[r3 * GNX + c] = z3;
    }
}

// ------------- elim body: role-split (coop path; 2 MMs per block) -----------
// Roles redundantly compute W (idle CUs; bitwise-identical), then:
//   role 0 (has_p):         X = cs*Cp*W -> MXT ; Slo = cs*Cp*X^T -> SLO[e]
//   role 1 (has_n):         Y = cs*W*Ce -> Msh ; Shi = cs*Ce^T*Y -> SHI[e]
//   role 2 (has_p&&has_n):  X = cs*Cp*W -> MXT ; Cn = -cs*X*Ce  -> CNW[e]
// Disjoint output slots -> no races; no extra grid syncs.
__device__ __forceinline__ void elim_role(float2* ldsb, float2* __restrict__ ws,
                                          const float* __restrict__ vel,
                                          float omega, int e, int lvl, int role) {
    const int s = 1 << lvl;
    const bool has_p = (e - s) >= 0;
    const bool has_n = (e + s) <= GNX - 1;
    if (role == 0 && !has_p) return;
    if (role == 1 && !has_n) return;
    if (role == 2 && !(has_p && has_n)) return;

    SHARED_VIEWS_FROM(ldsb)
    const int tid = threadIdx.x;
    const int c = tid & 63;
    const int q = tid >> 6;
    const int r0 = q, r1 = 16 + q, r2 = 32 + q, r3 = 48 + q;
    const float inv_h2 = 1.0f / (25.0f * 25.0f);
    const float c2 = inv_h2 * inv_h2;
    const float w2re = omega * omega * (1.0f - 0.0025f);
    const float w2im = -0.1f * omega * omega;

    float2 a0, a1, a2, a3, y0, y1, y2, y3, z0, z1, z2, z3;
    ELIM_W_PROLOGUE()

    Msh[r0][c] = a0; Msh[r1][c] = a1; Msh[r2][c] = a2; Msh[r3][c] = a3;
    __syncthreads();

    const int h = s >> 1;
    const int cbase = (lvl == 1) ? WS_SLO : WS_CNW;
    const float cs = (lvl == 1) ? -c2 : 1.0f;
    const float2* Cpg = ws + (size_t)(cbase + (has_p ? e - h : 0)) * MATN;
    const float2* Ceg = ws + (size_t)(cbase + (has_n ? e + h : 0)) * MATN;

    if (role == 0) {
        float2* Sl = ws + (size_t)(WS_SLO + e) * MATN;
        MM(y0, y1, y2, y3, AG_CP, BL_MSH)
        SCST(y0) SCST(y1) SCST(y2) SCST(y3)
        MXT[c][r0] = y0; MXT[c][r1] = y1;
        MXT[c][r2] = y2; MXT[c][r3] = y3;
        __syncthreads();
        MM(z0, z1, z2, z3, AG_CP, BL_MXT)
        SCST(z0) SCST(z1) SCST(z2) SCST(z3)
        Sl[r0 * GNX + c] = z0; Sl[r1 * GNX + c] = z1;
        Sl[r2 * GNX + c] = z2; Sl[r3 * GNX + c] = z3;
    } else if (role == 1) {
        float2* Sh = ws + (size_t)(WS_SHI + e) * MATN;
        MM(y0, y1, y2, y3, AL_MSH, BG_CE)
        SCST(y0) SCST(y1) SCST(y2) SCST(y3)
        __syncthreads();
        Msh[r0][c] = y0; Msh[r1][c] = y1;
        Msh[r2][c] = y2; Msh[r3][c] = y3;
        __syncthreads();
        MM(z0, z1, z2, z3, AG_CET, BL_MSH)
        SCST(z0) SCST(z1) SCST(z2) SCST(z3)
        Sh[r0 * GNX + c] = z0; Sh[r1 * GNX + c] = z1;
        Sh[r2 * GNX + c] = z2; Sh[r3 * GNX + c] = z3;
    } else {
        float2* Cn = ws + (size_t)(WS_CNW + e) * MATN;
        MM(y0, y1, y2, y3, AG_CP, BL_MSH)
        SCST(y0) SCST(y1) SCST(y2) SCST(y3)
        MXT[c][r0] = y0; MXT[c][r1] = y1;
        MXT[c][r2] = y2; MXT[c][r3] = y3;
        __syncthreads();
        MM(z0, z1, z2, z3, AL_MXT, BG_CE)
        SCST(z0) SCST(z1) SCST(z2) SCST(z3)
        Cn[r0 * GNX + c] = make_float2(-z0.x, -z0.y);
        Cn[r1 * GNX + c] = make_float2(-z1.x, -z1.y);
        Cn[r2 * GNX + c] = make_float2(-z2.x, -z2.y);
        Cn[r3 * GNX + c] = make_float2(-z3.x, -z3.y);
    }
}

// Fused L5 (e=34, has_p only) + final: Slo[34] never leaves registers.
__device__ __forceinline__ void tail_dev(float2* ldsb, float2* __restrict__ ws,
                                         const float* __restrict__ vel,
                                         const int* __restrict__ sxs,
                                         float omega, float amp,
                                         float* __restrict__ out, int out_size) {
    SHARED_VIEWS_FROM(ldsb)
    const int tid = threadIdx.x;
    const int c = tid & 63;
    const int q = tid >> 6;
    const int r0 = q, r1 = 16 + q, r2 = 32 + q, r3 = 48 + q;
    const float inv_h2 = 1.0f / (25.0f * 25.0f);
    const float c2 = inv_h2 * inv_h2;
    const float w2re = omega * omega * (1.0f - 0.0025f);
    const float w2im = -0.1f * omega * omega;
    float2 a0, a1, a2, a3, y0, y1, y2, y3, z0, z1, z2, z3;

    // L5: W34 = (D_34 - folds)^-1
    {
        const int e = 34, lvl = 5;
        ELIM_W_PROLOGUE()
    }
    Msh[r0][c] = a0; Msh[r1][c] = a1; Msh[r2][c] = a2; Msh[r3][c] = a3;
    __syncthreads();
    const float2* Cpg = ws + (size_t)(WS_CNW + 18) * MATN;  // C(2<->34) from L4
    MM(y0, y1, y2, y3, AG_CP, BL_MSH)        // X = Cn18 * W34   (cs = 1)
    MXT[c][r0] = y0; MXT[c][r1] = y1; MXT[c][r2] = y2; MXT[c][r3] = y3;
    __syncthreads();
    MM(z0, z1, z2, z3, AG_CP, BL_MXT)        // Slo[34] = Cn18 * X^T -> registers
    __syncthreads();                         // MXT reads done; scratch reusable

    // final: D~_2 = D_2 - folds(lp 0..4) - Slo34(regs)
    BDROW(a0, r0, 2) BDROW(a1, r1, 2) BDROW(a2, r2, 2) BDROW(a3, r3, 2)
    FOLD_CONTRIB(2, 5)
    a0.x -= z0.x; a0.y -= z0.y; a1.x -= z1.x; a1.y -= z1.y;
    a2.x -= z2.x; a2.y -= z2.y; a3.x -= z3.x; a3.y -= z3.y;
    INVERT()
    Msh[r0][c] = a0; Msh[r1][c] = a1; Msh[r2][c] = a2; Msh[r3][c] = a3;
    __syncthreads();
    // Graded: out[s*64 + x] = amp * Re(M[x, sxs[s]]) (r3/r4 forensics)
    for (int idx = tid; idx < GNSH * GNX; idx += NTH) {
        int sh_ = idx >> 6, x = idx & 63;
        int sx = sxs[sh_] & 63;
        if (idx < out_size) out[idx] = amp * Msh[x][sx].x;
    }
    for (int idx = GNSH * GNX + tid; idx < out_size; idx += NTH) out[idx] = 0.0f;
}

// ---------------- single cooperative kernel: role-split levels --------------
#define NBLK 48
__global__ __launch_bounds__(NTH) void bcr_coop(
    float2* __restrict__ ws, const float* __restrict__ vel,
    const int* __restrict__ sxs, const void* om_p, const void* amp_p,
    float* __restrict__ out, int out_size) {
    __shared__ float2 ldsbuf[8192];
    cg::grid_group grid = cg::this_grid();
    const int bid = (int)blockIdx.x;
    const int eidx = bid / 3, role = bid % 3;
    const float omega = scal_f(om_p);
    if (bid < 32) elim_dev(ldsbuf, ws, vel, omega, 1 + bid * 2, 0);  // L0
    grid.sync();
    if (eidx < 16) elim_role(ldsbuf, ws, vel, omega, 0 + eidx * 4, 1, role);
    grid.sync();
    if (eidx < 8)  elim_role(ldsbuf, ws, vel, omega, 6 + eidx * 8, 2, role);
    grid.sync();
    if (eidx < 4)  elim_role(ldsbuf, ws, vel, omega, 10 + eidx * 16, 3, role);
    grid.sync();
    if (eidx < 2)  elim_role(ldsbuf, ws, vel, omega, 18 + eidx * 32, 4, role);
    grid.sync();
    if (bid == 0)
        tail_dev(ldsbuf, ws, vel, sxs, omega, scal_f(amp_p), out, out_size);
}

// ---------------- fallback A: r17 multi-dispatch (proven 612us) -------------
__global__ __launch_bounds__(NTH) void bcr_elim(float2* __restrict__ ws,
                                                const float* __restrict__ vel,
                                                const void* om_p,
                                                int ebase, int estep, int lvl) {
    __shared__ float2 ldsbuf[8192];
    elim_dev(ldsbuf, ws, vel, scal_f(om_p),
             ebase + (int)blockIdx.x * estep, lvl);
}

__global__ __launch_bounds__(NTH) void bcr_final(
    float2* __restrict__ ws, const float* __restrict__ vel,
    const int* __restrict__ sxs, const void* om_p, const void* amp_p,
    float* __restrict__ out, int out_size) {
    __shared__ float2 ldsbuf[8192];
    SHARED_VIEWS_FROM(ldsbuf)
    const int tid = threadIdx.x;
    const int c = tid & 63;
    const int q = tid >> 6;
    const int r0 = q, r1 = 16 + q, r2 = 32 + q, r3 = 48 + q;
    const float omega = scal_f(om_p);
    const float amp = scal_f(amp_p);
    const float inv_h2 = 1.0f / (25.0f * 25.0f);
    const float c2 = inv_h2 * inv_h2;
    const float w2re = omega * omega * (1.0f - 0.0025f);
    const float w2im = -0.1f * omega * omega;
    float2 a0, a1, a2, a3;
    BDROW(a0, r0, 2) BDROW(a1, r1, 2) BDROW(a2, r2, 2) BDROW(a3, r3, 2)
    FOLD_CONTRIB(2, 6)
    INVERT()
    Msh[r0][c] = a0; Msh[r1][c] = a1; Msh[r2][c] = a2; Msh[r3][c] = a3;
    __syncthreads();
    for (int idx = tid; idx < GNSH * GNX; idx += NTH) {
        int sh_ = idx >> 6, x = idx & 63;
        int sx = sxs[sh_] & 63;
        if (idx < out_size) out[idx] = amp * Msh[x][sx].x;
    }
    for (int idx = GNSH * GNX + tid; idx < out_size; idx += NTH) out[idx] = 0.0f;
    (void)MXT;
}

// ---------------- fallback B: r13 single-block RGF --------------------------
__global__ __launch_bounds__(NTH) void rgf_mono(
    const float* __restrict__ vel, const int* __restrict__ sxs,
    const void* sy_p, const void* ry_p, const void* om_p, const void* amp_p,
    float* __restrict__ out, int out_size)
{
    __shared__ float2 ldsbuf[8192];
    SHARED_VIEWS_FROM(ldsbuf)
    const int tid = threadIdx.x;
    const int c = tid & 63;
    const int q = tid >> 6;
    const int r0 = q, r1 = 16 + q, r2 = 32 + q, r3 = 48 + q;

    const float omega = scal_f(om_p);
    const float amp = scal_f(amp_p);
    int jmid_raw = scal_i(sy_p);
    const int jmid = jmid_raw < 0 ? 0 : (jmid_raw > GNY - 1 ? GNY - 1 : jmid_raw);
    (void)ry_p;

    const float inv_h2 = 1.0f / (25.0f * 25.0f);
    const float c2 = inv_h2 * inv_h2;
    const float w2re = omega * omega * (1.0f - 0.0025f);
    const float w2im = -0.1f * omega * omega;

    float2 a0, a1, a2, a3;
    float2 g0 = {0,0}, g1 = {0,0}, g2 = {0,0}, g3 = {0,0};

#define BUILD(AE, GE, RE, J, USEPREV, USEGD) { \
    float2 v; \
    v.x = (USEPREV) ? -c2 * AE.x : 0.0f; \
    v.y = (USEPREV) ? -c2 * AE.y : 0.0f; \
    if (USEGD) { v.x -= c2 * GE.x; v.y -= c2 * GE.y; } \
    if ((RE) == c) { \
        float vv = vel[(J) * GNX + c]; \
        float iv2 = 1.0f / (vv * vv); \
        v.x += w2re * iv2 - 4.0f * inv_h2; \
        v.y += w2im * iv2; \
    } else if (((RE) - c) * ((RE) - c) == 1) { \
        v.x += inv_h2; \
    } \
    AE = v; }

#define BUILD4(J, USEPREV, USEGD) { \
    BUILD(a0, g0, r0, J, USEPREV, USEGD) \
    BUILD(a1, g1, r1, J, USEPREV, USEGD) \
    BUILD(a2, g2, r2, J, USEPREV, USEGD) \
    BUILD(a3, g3, r3, J, USEPREV, USEGD) }

    if (jmid > 0) {
        BUILD4(0, false, false)
        INVERT()
        for (int j = 1; j < jmid; ++j) { BUILD4(j, true, false) INVERT() }
        g0 = a0; g1 = a1; g2 = a2; g3 = a3;
    }
    const bool have_up = (jmid < GNY - 1);
    if (have_up) {
        BUILD4(GNY - 1, false, false)
        INVERT()
        for (int m = GNY - 2; m > jmid; --m) { BUILD4(m, true, false) INVERT() }
    }
    BUILD4(jmid, have_up, jmid > 0)
    INVERT()

    Msh[r0][c] = a0; Msh[r1][c] = a1; Msh[r2][c] = a2; Msh[r3][c] = a3;
    __syncthreads();

    for (int idx = tid; idx < GNSH * GNX; idx += NTH) {
        int s_ = idx >> 6, x = idx & 63;
        int sx = sxs[s_] & 63;
        if (idx < out_size) out[idx] = amp * Msh[x][sx].x;
    }
    for (int idx = GNSH * GNX + tid; idx < out_size; idx += NTH) out[idx] = 0.0f;
    (void)MXT;
}

extern "C" void kernel_launch(void* const* d_in, const int* in_sizes, int n_in,
                              void* d_out, int out_size, void* d_ws, size_t ws_size,
                              hipStream_t stream) {
    (void)in_sizes; (void)n_in;
    const float* vel = (const float*)d_in[0];
    const int* sxs = (const int*)d_in[1];
    const size_t need = (size_t)WS_MATS * MATN * sizeof(float2);  // 6 MB
    if (ws_size >= need) {
        float2* wsp = (float2*)d_ws;
        const float* velp = vel;
        const int* sxsp = sxs;
        const void* omp = d_in[4];
        const void* ampp = d_in[5];
        float* outp = (float*)d_out;
        int osz = out_size;
        void* args[] = {&wsp, (void*)&velp, (void*)&sxsp,
                        (void*)&omp, (void*)&ampp, &outp, &osz};
        hipError_t err = hipLaunchCooperativeKernel(
            (const void*)bcr_coop, dim3(NBLK), dim3(NTH), args, 0, stream);
        if (err == hipSuccess) return;
        (void)hipGetLastError();  // clear; fall back to multi-dispatch (r17)
        static const int EL[6][3] = {
            {32, 1, 2}, {16, 0, 4}, {8, 6, 8},
            {4, 10, 16}, {2, 18, 32}, {1, 34, 64}};
        for (int l = 0; l < 6; ++l) {
            bcr_elim<<<dim3(EL[l][0]), dim3(NTH), 0, stream>>>(
                wsp, vel, d_in[4], EL[l][1], EL[l][2], l);
        }
        bcr_final<<<dim3(1), dim3(NTH), 0, stream>>>(
            wsp, vel, sxs, d_in[4], d_in[5], (float*)d_out, out_size);
    } else {
        rgf_mono<<<dim3(1), dim3(NTH), 0, stream>>>(
            vel, sxs, d_in[2], d_in[3], d_in[4], d_in[5], (float*)d_out, out_size);
    }
}